// Round 6
// baseline (277.108 us; speedup 1.0000x reference)
//
#include <hip/hip_runtime.h>

// Problem constants: B=2, T=2048, C=1024, H=16, HS=64. fp32 I/O, bf16 internal.
#define TB 2
#define TT 2048
#define TC 1024
#define TH 16
#define THS 64

typedef short bf16x8 __attribute__((ext_vector_type(8)));
typedef float f32x4 __attribute__((ext_vector_type(4)));

// Q pre-scale: (1/sqrt(C)) * log2(e), folded into Qb at QKV-GEMM epilogue
#define QSCALE 0.0450842200278f

// round-to-nearest-even fp32 -> bf16 bit pattern
__device__ inline unsigned short f2b(float f) {
    unsigned u = __builtin_bit_cast(unsigned, f);
    unsigned r = (u + 0x7fffu + ((u >> 16) & 1u)) >> 16;
    return (unsigned short)r;
}

// async global->LDS 16B/lane. LDS dest contract: wave-uniform base + lane*16.
__device__ inline void gl_lds16(const unsigned short* g, unsigned short* l) {
    __builtin_amdgcn_global_load_lds(
        (const __attribute__((address_space(1))) unsigned int*)(g),
        (__attribute__((address_space(3))) unsigned int*)(l), 16, 0, 0);
}

// 16-lane all-reduce sum via DPP row_ror butterfly (once per row at kernel end)
__device__ inline float dpp_sum16(float x) {
    int t;
    t = __builtin_amdgcn_update_dpp(0, __builtin_bit_cast(int, x), 0x128, 0xf, 0xf, true);
    x += __builtin_bit_cast(float, t);
    t = __builtin_amdgcn_update_dpp(0, __builtin_bit_cast(int, x), 0x124, 0xf, 0xf, true);
    x += __builtin_bit_cast(float, t);
    t = __builtin_amdgcn_update_dpp(0, __builtin_bit_cast(int, x), 0x122, 0xf, 0xf, true);
    x += __builtin_bit_cast(float, t);
    t = __builtin_amdgcn_update_dpp(0, __builtin_bit_cast(int, x), 0x121, 0xf, 0xf, true);
    x += __builtin_bit_cast(float, t);
    return x;
}

// ---------------- convert fp32 -> bf16, 8 elements/thread ----------------
__global__ void cvt_bf16_k(const float* __restrict__ in, unsigned short* __restrict__ out) {
    const int i = blockIdx.x * blockDim.x + threadIdx.x;
    const float4* p = (const float4*)in + (size_t)i * 2;
    const float4 a = p[0], b = p[1];
    bf16x8 v;
    v[0] = (short)f2b(a.x); v[1] = (short)f2b(a.y);
    v[2] = (short)f2b(a.z); v[3] = (short)f2b(a.w);
    v[4] = (short)f2b(b.x); v[5] = (short)f2b(b.y);
    v[6] = (short)f2b(b.z); v[7] = (short)f2b(b.w);
    *(bf16x8*)(out + (size_t)i * 8) = v;
}

// ------------- transpose + convert: fp32 in[R][Cc] -> bf16 out[Cc][R] -------------
__global__ void transpose_cvt_k(const float* __restrict__ in,
                                unsigned short* __restrict__ out, int R, int Cc) {
    __shared__ float tile[32][33];
    const int tx = threadIdx.x, ty = threadIdx.y;
    const int r0 = blockIdx.y * 32, c0 = blockIdx.x * 32;
#pragma unroll
    for (int i = 0; i < 4; i++)
        tile[ty + i * 8][tx] = in[(size_t)(r0 + ty + i * 8) * Cc + c0 + tx];
    __syncthreads();
#pragma unroll
    for (int i = 0; i < 4; i++)
        out[(size_t)(c0 + ty + i * 8) * R + r0 + tx] = f2b(tile[tx][ty + i * 8]);
}

// ------- QKV GEMM: C = Xb * Wq_t^T, scatter epilogue -> K/Q [B,H,T,64], V^T ------
// Q is pre-scaled by QSCALE here (free) so attn's softmax needs no multiply.
__global__ __launch_bounds__(256) void gemm_qkv(
    const unsigned short* __restrict__ A, const unsigned short* __restrict__ Bt, int K,
    unsigned short* __restrict__ outK, unsigned short* __restrict__ outQ,
    unsigned short* __restrict__ outV) {
    __shared__ __align__(16) unsigned short As[128 * 32];
    __shared__ __align__(16) unsigned short Bs[128 * 32];

    const int tid = threadIdx.x;
    const int wave = tid >> 6, lane = tid & 63;
    const int quad = lane >> 4, l16 = lane & 15;
    const int wm = (wave >> 1) * 64, wn = (wave & 1) * 64;
    const int m0 = blockIdx.y * 128, n0 = blockIdx.x * 128;

    const f32x4 vzero = {0.f, 0.f, 0.f, 0.f};
    f32x4 acc[4][4];
#pragma unroll
    for (int i = 0; i < 4; i++)
#pragma unroll
        for (int j = 0; j < 4; j++) acc[i][j] = vzero;

    const int nk = K >> 5;
    for (int kt = 0; kt < nk; ++kt) {
        const int k0 = kt * 32;
        __syncthreads();
#pragma unroll
        for (int it = 0; it < 2; ++it) {
            const int chunk = tid + it * 256;
            const int r = chunk >> 2, col = (chunk & 3) * 8;
            gl_lds16(A + (size_t)(m0 + r) * K + k0 + col, &As[chunk * 8]);
            gl_lds16(Bt + (size_t)(n0 + r) * K + k0 + col, &Bs[chunk * 8]);
        }
        __syncthreads();
        bf16x8 af[4], bfr[4];
#pragma unroll
        for (int f = 0; f < 4; ++f) {
            af[f] = *(const bf16x8*)(&As[(wm + f * 16 + l16) * 32 + quad * 8]);
            bfr[f] = *(const bf16x8*)(&Bs[(wn + f * 16 + l16) * 32 + quad * 8]);
        }
#pragma unroll
        for (int fm = 0; fm < 4; ++fm)
#pragma unroll
            for (int fn = 0; fn < 4; ++fn)
                acc[fm][fn] = __builtin_amdgcn_mfma_f32_16x16x32_bf16(
                    af[fm], bfr[fn], acc[fm][fn], 0, 0, 0);
    }

    // epilogue: C/D layout col=lane&15, row=quad*4+reg
#pragma unroll
    for (int fm = 0; fm < 4; ++fm) {
#pragma unroll
        for (int fn = 0; fn < 4; ++fn) {
#pragma unroll
            for (int r = 0; r < 4; ++r) {
                const int row = m0 + wm + fm * 16 + quad * 4 + r;
                const int col = n0 + wn + fn * 16 + l16;
                const float val = acc[fm][fn][r];
                const int b = row >> 11, t = row & (TT - 1);
                const int chunkc = col >> 10, cc = col & (TC - 1);
                const int hh = cc >> 6, d = cc & 63;
                const size_t bht = (size_t)((b * TH + hh) * TT + t);
                if (chunkc == 0)
                    outK[bht * THS + d] = f2b(val);  // module split order: K first!
                else if (chunkc == 1)
                    outQ[bht * THS + d] = f2b(val * QSCALE);  // pre-scaled Q
                else
                    outV[((size_t)((b * TH + hh) * THS + d)) * TT + t] = f2b(val);  // V^T
            }
        }
    }
}

// ------- proj GEMM: out[M,N] = A[M,K] * Bt[N,K]^T, 128x64 tile, fp32 out ---------
// 64-wide N tile -> 512 blocks (2 blocks/CU) so barrier drains overlap across blocks.
__global__ __launch_bounds__(256) void gemm_proj(
    const unsigned short* __restrict__ A, const unsigned short* __restrict__ Bt,
    int M, int N, int K, float* __restrict__ outF) {
    __shared__ __align__(16) unsigned short As[128 * 32];
    __shared__ __align__(16) unsigned short Bs[64 * 32];

    const int tid = threadIdx.x;
    const int wave = tid >> 6, lane = tid & 63;
    const int quad = lane >> 4, l16 = lane & 15;
    const int wm = wave * 32;  // 4 waves cover 128 rows; all waves cover 64 cols
    const int m0 = blockIdx.y * 128, n0 = blockIdx.x * 64;

    const f32x4 vzero = {0.f, 0.f, 0.f, 0.f};
    f32x4 acc[2][4];
#pragma unroll
    for (int i = 0; i < 2; i++)
#pragma unroll
        for (int j = 0; j < 4; j++) acc[i][j] = vzero;

    const int nk = K >> 5;
    for (int kt = 0; kt < nk; ++kt) {
        const int k0 = kt * 32;
        __syncthreads();
#pragma unroll
        for (int it = 0; it < 2; ++it) {
            const int chunk = tid + it * 256;
            const int r = chunk >> 2, col = (chunk & 3) * 8;
            gl_lds16(A + (size_t)(m0 + r) * K + k0 + col, &As[chunk * 8]);
        }
        {
            const int r = tid >> 2, col = (tid & 3) * 8;
            gl_lds16(Bt + (size_t)(n0 + r) * K + k0 + col, &Bs[tid * 8]);
        }
        __syncthreads();
        bf16x8 af[2], bfr[4];
#pragma unroll
        for (int f = 0; f < 2; ++f)
            af[f] = *(const bf16x8*)(&As[(wm + f * 16 + l16) * 32 + quad * 8]);
#pragma unroll
        for (int f = 0; f < 4; ++f)
            bfr[f] = *(const bf16x8*)(&Bs[(f * 16 + l16) * 32 + quad * 8]);
#pragma unroll
        for (int fm = 0; fm < 2; ++fm)
#pragma unroll
            for (int fn = 0; fn < 4; ++fn)
                acc[fm][fn] = __builtin_amdgcn_mfma_f32_16x16x32_bf16(
                    af[fm], bfr[fn], acc[fm][fn], 0, 0, 0);
    }

#pragma unroll
    for (int fm = 0; fm < 2; ++fm)
#pragma unroll
        for (int fn = 0; fn < 4; ++fn)
#pragma unroll
            for (int r = 0; r < 4; ++r) {
                const int row = m0 + wm + fm * 16 + quad * 4 + r;
                const int col = n0 + fn * 16 + l16;
                outF[(size_t)row * N + col] = acc[fm][fn][r];
            }
}

// ---- flash attention, no-max softmax + in-block split-K, 32 q-rows/block ----
// Per-wave LDS union: P staging (4.6 KB, loop phase) aliases the wave's o-partial
// region (8.4 KB, merge phase). Safe: a wave writes o-partials only after its own
// last aP read; other waves read them only after __syncthreads.
__global__ __launch_bounds__(256, 4) void attn_k(
    const unsigned short* __restrict__ Qb, const unsigned short* __restrict__ Kb,
    const unsigned short* __restrict__ Vt, unsigned short* __restrict__ AO) {
    __shared__ __align__(16) float U[4][2112];  // per-wave union: P (loop) / oS (merge)
    __shared__ float lS[4][32];                 // per-wave l per row

    const int tid = threadIdx.x;
    const int w = tid >> 6, lane = tid & 63;
    const int quad = lane >> 4, l16 = lane & 15;
    const int bh = blockIdx.x;        // 0..31 (fastest: spreads long blocks)
    const int qtt = 63 - blockIdx.y;  // reversed: longest blocks dispatch first
    const int q0 = qtt * 32;
    const unsigned short* Qh = Qb + (size_t)bh * TT * THS;
    const unsigned short* Kh = Kb + (size_t)bh * TT * THS;
    const unsigned short* Vh = Vt + (size_t)bh * THS * TT;

    bf16x8 aQ[2][2];
#pragma unroll
    for (int rt = 0; rt < 2; ++rt)
#pragma unroll
        for (int ks = 0; ks < 2; ++ks)
            aQ[rt][ks] = *(const bf16x8*)(
                Qh + (size_t)(q0 + rt * 16 + l16) * THS + ks * 32 + quad * 8);

    const float NEGINF = -__builtin_inff();
    const f32x4 vzero = {0.f, 0.f, 0.f, 0.f};
    f32x4 o[2][4];
    float lp[2][4];  // per-lane l partials
#pragma unroll
    for (int rt = 0; rt < 2; ++rt)
#pragma unroll
        for (int i = 0; i < 4; i++) { o[rt][i] = vzero; lp[rt][i] = 0.f; }

    const int nkt = (qtt >> 1) + 1;  // 64-key tiles covering [0, q0+32)
    for (int kt = w; kt < nkt; kt += 4) {
        const int t0 = kt * 64;
        // ---- K and V fragment loads (shared across both row-tiles) ----
        bf16x8 bK[8], bV[8];
#pragma unroll
        for (int nt = 0; nt < 4; ++nt)
#pragma unroll
            for (int ks = 0; ks < 2; ++ks) {
                bK[nt * 2 + ks] = *(const bf16x8*)(
                    Kh + (size_t)(t0 + nt * 16 + l16) * THS + ks * 32 + quad * 8);
                bV[nt * 2 + ks] = *(const bf16x8*)(
                    Vh + (size_t)(nt * 16 + l16) * TT + t0 + ks * 32 + quad * 8);
            }
        const bool needmask = (kt == nkt - 1);  // only the diagonal tile masks
#pragma unroll
        for (int rt = 0; rt < 2; ++rt) {
            f32x4 s[4];
#pragma unroll
            for (int nt = 0; nt < 4; ++nt) s[nt] = vzero;
#pragma unroll
            for (int ks = 0; ks < 2; ++ks)
#pragma unroll
                for (int nt = 0; nt < 4; ++nt)
                    s[nt] = __builtin_amdgcn_mfma_f32_16x16x32_bf16(
                        aQ[rt][ks], bK[nt * 2 + ks], s[nt], 0, 0, 0);
            // ---- no-max softmax: Q pre-scaled, p = exp2(s), lane-partial l ----
            unsigned short* Pw = (unsigned short*)&U[w][0] + rt * 1152;
#pragma unroll
            for (int r = 0; r < 4; ++r) {
                const int row = q0 + rt * 16 + quad * 4 + r;
                float v0 = s[0][r], v1 = s[1][r], v2 = s[2][r], v3 = s[3][r];
                if (needmask) {
                    if (t0 + l16 > row) v0 = NEGINF;
                    if (t0 + 16 + l16 > row) v1 = NEGINF;
                    if (t0 + 32 + l16 > row) v2 = NEGINF;
                    if (t0 + 48 + l16 > row) v3 = NEGINF;
                }
                const float p0 = __builtin_amdgcn_exp2f(v0);
                const float p1 = __builtin_amdgcn_exp2f(v1);
                const float p2 = __builtin_amdgcn_exp2f(v2);
                const float p3 = __builtin_amdgcn_exp2f(v3);
                lp[rt][r] += (p0 + p1) + (p2 + p3);
                const int pr = (quad * 4 + r) * 72;
                Pw[pr + l16] = f2b(p0);
                Pw[pr + 16 + l16] = f2b(p1);
                Pw[pr + 32 + l16] = f2b(p2);
                Pw[pr + 48 + l16] = f2b(p3);
            }
            asm volatile("s_waitcnt lgkmcnt(0)" ::: "memory");  // per-wave P visibility
            bf16x8 aP[2];
            aP[0] = *(const bf16x8*)(Pw + l16 * 72 + quad * 8);
            aP[1] = *(const bf16x8*)(Pw + l16 * 72 + 32 + quad * 8);
#pragma unroll
            for (int ks = 0; ks < 2; ++ks)
#pragma unroll
                for (int nt = 0; nt < 4; ++nt)
                    o[rt][nt] = __builtin_amdgcn_mfma_f32_16x16x32_bf16(
                        aP[ks], bV[nt * 2 + ks], o[rt][nt], 0, 0, 0);
        }
    }

    // ---- reduce l (once), store o partials into this wave's union region ----
#pragma unroll
    for (int rt = 0; rt < 2; ++rt)
#pragma unroll
        for (int r = 0; r < 4; ++r) {
            const float lsum = dpp_sum16(lp[rt][r]);
            const int row = rt * 16 + quad * 4 + r;
            if (l16 == 0) lS[w][row] = lsum;
#pragma unroll
            for (int nt = 0; nt < 4; ++nt)
                U[w][row * 66 + nt * 16 + l16] = o[rt][nt][r];
        }
    __syncthreads();

    // ---- merge (plain sums — exact); wave w -> cols [w*16, +16) ----
    const int b = bh >> 4, h = bh & 15;
    const int col = w * 16 + l16;
#pragma unroll
    for (int rr = 0; rr < 8; ++rr) {
        const int row = quad * 8 + rr;
        const float L = (lS[0][row] + lS[1][row]) + (lS[2][row] + lS[3][row]);
        const float O = (U[0][row * 66 + col] + U[1][row * 66 + col]) +
                        (U[2][row * 66 + col] + U[3][row * 66 + col]);
        const int t = q0 + row;
        AO[((size_t)(b * TT + t)) * TC + h * 64 + col] = f2b(O / L);
    }
}

extern "C" void kernel_launch(void* const* d_in, const int* in_sizes, int n_in,
                              void* d_out, int out_size, void* d_ws, size_t ws_size,
                              hipStream_t stream) {
    const float* X = (const float*)d_in[0];      // [2,2048,1024] fp32
    const float* Wqkv = (const float*)d_in[1];   // [1024,3072] fp32
    const float* Wproj = (const float*)d_in[2];  // [1024,1024] fp32
    float* out = (float*)d_out;                  // [2,2048,1024] fp32

    unsigned short* ws = (unsigned short*)d_ws;
    unsigned short* Xb = ws;                           // [4096,1024] bf16
    unsigned short* Wq_t = Xb + 4096 * 1024;           // [3072,1024] bf16
    unsigned short* Wp_t = Wq_t + 3072 * 1024;         // [1024,1024] bf16
    unsigned short* Qb = Wp_t + 1024 * 1024;           // [B,H,T,64] (pre-scaled)
    unsigned short* Kb = Qb + TB * TH * TT * THS;      // [B,H,T,64]
    unsigned short* Vt = Kb + TB * TH * TT * THS;      // [B,H,64,T]
    unsigned short* AO = Vt + TB * TH * TT * THS;      // [B,T,C] bf16

    cvt_bf16_k<<<dim3((4096 * 1024) / (8 * 256)), 256, 0, stream>>>(X, Xb);
    transpose_cvt_k<<<dim3(3072 / 32, 1024 / 32), dim3(32, 8), 0, stream>>>(Wqkv, Wq_t, 1024, 3072);
    transpose_cvt_k<<<dim3(1024 / 32, 1024 / 32), dim3(32, 8), 0, stream>>>(Wproj, Wp_t, 1024, 1024);
    gemm_qkv<<<dim3(3072 / 128, 4096 / 128), 256, 0, stream>>>(Xb, Wq_t, 1024, Kb, Qb, Vt);
    attn_k<<<dim3(32, 64), 256, 0, stream>>>(Qb, Kb, Vt, AO);
    gemm_proj<<<dim3(1024 / 64, 4096 / 128), 256, 0, stream>>>(
        AO, Wp_t, 4096, 1024, 1024, out);
}

// Round 7
// 215.466 us; speedup vs baseline: 1.2861x; 1.2861x over previous
//
#include <hip/hip_runtime.h>

// Problem constants: B=2, T=2048, C=1024, H=16, HS=64. fp32 I/O, bf16 internal.
#define TB 2
#define TT 2048
#define TC 1024
#define TH 16
#define THS 64

typedef short bf16x8 __attribute__((ext_vector_type(8)));
typedef float f32x4 __attribute__((ext_vector_type(4)));

// Q pre-scale: (1/sqrt(C)) * log2(e), folded into Qb at QKV-GEMM epilogue
#define QSCALE 0.0450842200278f

// round-to-nearest-even fp32 -> bf16 bit pattern
__device__ inline unsigned short f2b(float f) {
    unsigned u = __builtin_bit_cast(unsigned, f);
    unsigned r = (u + 0x7fffu + ((u >> 16) & 1u)) >> 16;
    return (unsigned short)r;
}

// async global->LDS 16B/lane. LDS dest contract: wave-uniform base + lane*16.
__device__ inline void gl_lds16(const unsigned short* g, unsigned short* l) {
    __builtin_amdgcn_global_load_lds(
        (const __attribute__((address_space(1))) unsigned int*)(g),
        (__attribute__((address_space(3))) unsigned int*)(l), 16, 0, 0);
}

// 16-lane all-reduce sum via DPP row_ror butterfly (once per row at kernel end)
__device__ inline float dpp_sum16(float x) {
    int t;
    t = __builtin_amdgcn_update_dpp(0, __builtin_bit_cast(int, x), 0x128, 0xf, 0xf, true);
    x += __builtin_bit_cast(float, t);
    t = __builtin_amdgcn_update_dpp(0, __builtin_bit_cast(int, x), 0x124, 0xf, 0xf, true);
    x += __builtin_bit_cast(float, t);
    t = __builtin_amdgcn_update_dpp(0, __builtin_bit_cast(int, x), 0x122, 0xf, 0xf, true);
    x += __builtin_bit_cast(float, t);
    t = __builtin_amdgcn_update_dpp(0, __builtin_bit_cast(int, x), 0x121, 0xf, 0xf, true);
    x += __builtin_bit_cast(float, t);
    return x;
}

// ---------------- convert fp32 -> bf16, 8 elements/thread ----------------
__global__ void cvt_bf16_k(const float* __restrict__ in, unsigned short* __restrict__ out) {
    const int i = blockIdx.x * blockDim.x + threadIdx.x;
    const float4* p = (const float4*)in + (size_t)i * 2;
    const float4 a = p[0], b = p[1];
    bf16x8 v;
    v[0] = (short)f2b(a.x); v[1] = (short)f2b(a.y);
    v[2] = (short)f2b(a.z); v[3] = (short)f2b(a.w);
    v[4] = (short)f2b(b.x); v[5] = (short)f2b(b.y);
    v[6] = (short)f2b(b.z); v[7] = (short)f2b(b.w);
    *(bf16x8*)(out + (size_t)i * 8) = v;
}

// ------------- transpose + convert: fp32 in[R][Cc] -> bf16 out[Cc][R] -------------
__global__ void transpose_cvt_k(const float* __restrict__ in,
                                unsigned short* __restrict__ out, int R, int Cc) {
    __shared__ float tile[32][33];
    const int tx = threadIdx.x, ty = threadIdx.y;
    const int r0 = blockIdx.y * 32, c0 = blockIdx.x * 32;
#pragma unroll
    for (int i = 0; i < 4; i++)
        tile[ty + i * 8][tx] = in[(size_t)(r0 + ty + i * 8) * Cc + c0 + tx];
    __syncthreads();
#pragma unroll
    for (int i = 0; i < 4; i++)
        out[(size_t)(c0 + ty + i * 8) * R + r0 + tx] = f2b(tile[tx][ty + i * 8]);
}

// ------ V transpose: Vb[bh][t][d] -> Vt[bh][d][t], bf16, coalesced both sides ----
__global__ void vt_k(const unsigned short* __restrict__ Vb,
                     unsigned short* __restrict__ Vt) {
    __shared__ unsigned short tile[32][33];
    const int tx = threadIdx.x, ty = threadIdx.y;
    const int d0 = blockIdx.x * 32, t0 = blockIdx.y * 32, bh = blockIdx.z;
    const unsigned short* src = Vb + (size_t)bh * TT * THS;
    unsigned short* dst = Vt + (size_t)bh * THS * TT;
#pragma unroll
    for (int i = 0; i < 4; i++)
        tile[ty + i * 8][tx] = src[(size_t)(t0 + ty + i * 8) * THS + d0 + tx];
    __syncthreads();
#pragma unroll
    for (int i = 0; i < 4; i++)
        dst[(size_t)(d0 + ty + i * 8) * TT + t0 + tx] = tile[tx][ty + i * 8];
}

// ------- QKV GEMM: C = Xb * Wq_t^T, scatter epilogue -> K/Q/V [B,H,T,64] ---------
// All three outputs stored d-contiguous (coalesced); V transposed by vt_k after.
__global__ __launch_bounds__(256) void gemm_qkv(
    const unsigned short* __restrict__ A, const unsigned short* __restrict__ Bt, int K,
    unsigned short* __restrict__ outK, unsigned short* __restrict__ outQ,
    unsigned short* __restrict__ outV) {
    __shared__ __align__(16) unsigned short As[128 * 32];
    __shared__ __align__(16) unsigned short Bs[128 * 32];

    const int tid = threadIdx.x;
    const int wave = tid >> 6, lane = tid & 63;
    const int quad = lane >> 4, l16 = lane & 15;
    const int wm = (wave >> 1) * 64, wn = (wave & 1) * 64;
    const int m0 = blockIdx.y * 128, n0 = blockIdx.x * 128;

    const f32x4 vzero = {0.f, 0.f, 0.f, 0.f};
    f32x4 acc[4][4];
#pragma unroll
    for (int i = 0; i < 4; i++)
#pragma unroll
        for (int j = 0; j < 4; j++) acc[i][j] = vzero;

    const int nk = K >> 5;
    for (int kt = 0; kt < nk; ++kt) {
        const int k0 = kt * 32;
        __syncthreads();
#pragma unroll
        for (int it = 0; it < 2; ++it) {
            const int chunk = tid + it * 256;
            const int r = chunk >> 2, col = (chunk & 3) * 8;
            gl_lds16(A + (size_t)(m0 + r) * K + k0 + col, &As[chunk * 8]);
            gl_lds16(Bt + (size_t)(n0 + r) * K + k0 + col, &Bs[chunk * 8]);
        }
        __syncthreads();
        bf16x8 af[4], bfr[4];
#pragma unroll
        for (int f = 0; f < 4; ++f) {
            af[f] = *(const bf16x8*)(&As[(wm + f * 16 + l16) * 32 + quad * 8]);
            bfr[f] = *(const bf16x8*)(&Bs[(wn + f * 16 + l16) * 32 + quad * 8]);
        }
#pragma unroll
        for (int fm = 0; fm < 4; ++fm)
#pragma unroll
            for (int fn = 0; fn < 4; ++fn)
                acc[fm][fn] = __builtin_amdgcn_mfma_f32_16x16x32_bf16(
                    af[fm], bfr[fn], acc[fm][fn], 0, 0, 0);
    }

    // epilogue: C/D layout col=lane&15, row=quad*4+reg
#pragma unroll
    for (int fm = 0; fm < 4; ++fm) {
#pragma unroll
        for (int fn = 0; fn < 4; ++fn) {
#pragma unroll
            for (int r = 0; r < 4; ++r) {
                const int row = m0 + wm + fm * 16 + quad * 4 + r;
                const int col = n0 + wn + fn * 16 + l16;
                const float val = acc[fm][fn][r];
                const int b = row >> 11, t = row & (TT - 1);
                const int chunkc = col >> 10, cc = col & (TC - 1);
                const int hh = cc >> 6, d = cc & 63;
                const size_t idx = (size_t)((b * TH + hh) * TT + t) * THS + d;
                if (chunkc == 0)
                    outK[idx] = f2b(val);  // module split order: K first!
                else if (chunkc == 1)
                    outQ[idx] = f2b(val * QSCALE);  // pre-scaled Q
                else
                    outV[idx] = f2b(val);  // coalesced; vt_k transposes after
            }
        }
    }
}

// ------- proj GEMM: out[M,N] = A[M,K] * Bt[N,K]^T, 128x64 tile, fp32 out ---------
__global__ __launch_bounds__(256) void gemm_proj(
    const unsigned short* __restrict__ A, const unsigned short* __restrict__ Bt,
    int M, int N, int K, float* __restrict__ outF) {
    __shared__ __align__(16) unsigned short As[128 * 32];
    __shared__ __align__(16) unsigned short Bs[64 * 32];

    const int tid = threadIdx.x;
    const int wave = tid >> 6, lane = tid & 63;
    const int quad = lane >> 4, l16 = lane & 15;
    const int wm = wave * 32;
    const int m0 = blockIdx.y * 128, n0 = blockIdx.x * 64;

    const f32x4 vzero = {0.f, 0.f, 0.f, 0.f};
    f32x4 acc[2][4];
#pragma unroll
    for (int i = 0; i < 2; i++)
#pragma unroll
        for (int j = 0; j < 4; j++) acc[i][j] = vzero;

    const int nk = K >> 5;
    for (int kt = 0; kt < nk; ++kt) {
        const int k0 = kt * 32;
        __syncthreads();
#pragma unroll
        for (int it = 0; it < 2; ++it) {
            const int chunk = tid + it * 256;
            const int r = chunk >> 2, col = (chunk & 3) * 8;
            gl_lds16(A + (size_t)(m0 + r) * K + k0 + col, &As[chunk * 8]);
        }
        {
            const int r = tid >> 2, col = (tid & 3) * 8;
            gl_lds16(Bt + (size_t)(n0 + r) * K + k0 + col, &Bs[tid * 8]);
        }
        __syncthreads();
        bf16x8 af[2], bfr[4];
#pragma unroll
        for (int f = 0; f < 2; ++f)
            af[f] = *(const bf16x8*)(&As[(wm + f * 16 + l16) * 32 + quad * 8]);
#pragma unroll
        for (int f = 0; f < 4; ++f)
            bfr[f] = *(const bf16x8*)(&Bs[(f * 16 + l16) * 32 + quad * 8]);
#pragma unroll
        for (int fm = 0; fm < 2; ++fm)
#pragma unroll
            for (int fn = 0; fn < 4; ++fn)
                acc[fm][fn] = __builtin_amdgcn_mfma_f32_16x16x32_bf16(
                    af[fm], bfr[fn], acc[fm][fn], 0, 0, 0);
    }

#pragma unroll
    for (int fm = 0; fm < 2; ++fm)
#pragma unroll
        for (int fn = 0; fn < 4; ++fn)
#pragma unroll
            for (int r = 0; r < 4; ++r) {
                const int row = m0 + wm + fm * 16 + quad * 4 + r;
                const int col = n0 + fn * 16 + l16;
                outF[(size_t)row * N + col] = acc[fm][fn][r];
            }
}

// ---- flash attention, no-max softmax + in-block split-K, 32 q-rows/block ----
// LDS union (34.3 KB) -> 4 blocks/CU; min-waves=3 so compiler does NOT spill
// (round 6 post-mortem: (256,4) clamped VGPR 84->64 and spilled 450 MB to scratch).
__global__ __launch_bounds__(256, 3) void attn_k(
    const unsigned short* __restrict__ Qb, const unsigned short* __restrict__ Kb,
    const unsigned short* __restrict__ Vt, unsigned short* __restrict__ AO) {
    __shared__ __align__(16) float U[4][2112];  // per-wave union: P (loop) / oS (merge)
    __shared__ float lS[4][32];                 // per-wave l per row

    const int tid = threadIdx.x;
    const int w = tid >> 6, lane = tid & 63;
    const int quad = lane >> 4, l16 = lane & 15;
    const int bh = blockIdx.x;        // 0..31 (fastest: spreads long blocks)
    const int qtt = 63 - blockIdx.y;  // reversed: longest blocks dispatch first
    const int q0 = qtt * 32;
    const unsigned short* Qh = Qb + (size_t)bh * TT * THS;
    const unsigned short* Kh = Kb + (size_t)bh * TT * THS;
    const unsigned short* Vh = Vt + (size_t)bh * THS * TT;

    bf16x8 aQ[2][2];
#pragma unroll
    for (int rt = 0; rt < 2; ++rt)
#pragma unroll
        for (int ks = 0; ks < 2; ++ks)
            aQ[rt][ks] = *(const bf16x8*)(
                Qh + (size_t)(q0 + rt * 16 + l16) * THS + ks * 32 + quad * 8);

    const float NEGINF = -__builtin_inff();
    const f32x4 vzero = {0.f, 0.f, 0.f, 0.f};
    f32x4 o[2][4];
    float lp[2][4];  // per-lane l partials
#pragma unroll
    for (int rt = 0; rt < 2; ++rt)
#pragma unroll
        for (int i = 0; i < 4; i++) { o[rt][i] = vzero; lp[rt][i] = 0.f; }

    const int nkt = (qtt >> 1) + 1;  // 64-key tiles covering [0, q0+32)
    for (int kt = w; kt < nkt; kt += 4) {
        const int t0 = kt * 64;
        // ---- K and V fragment loads (shared across both row-tiles) ----
        bf16x8 bK[8], bV[8];
#pragma unroll
        for (int nt = 0; nt < 4; ++nt)
#pragma unroll
            for (int ks = 0; ks < 2; ++ks) {
                bK[nt * 2 + ks] = *(const bf16x8*)(
                    Kh + (size_t)(t0 + nt * 16 + l16) * THS + ks * 32 + quad * 8);
                bV[nt * 2 + ks] = *(const bf16x8*)(
                    Vh + (size_t)(nt * 16 + l16) * TT + t0 + ks * 32 + quad * 8);
            }
        const bool needmask = (kt == nkt - 1);  // only the diagonal tile masks
#pragma unroll
        for (int rt = 0; rt < 2; ++rt) {
            f32x4 s[4];
#pragma unroll
            for (int nt = 0; nt < 4; ++nt) s[nt] = vzero;
#pragma unroll
            for (int ks = 0; ks < 2; ++ks)
#pragma unroll
                for (int nt = 0; nt < 4; ++nt)
                    s[nt] = __builtin_amdgcn_mfma_f32_16x16x32_bf16(
                        aQ[rt][ks], bK[nt * 2 + ks], s[nt], 0, 0, 0);
            // ---- no-max softmax: Q pre-scaled, p = exp2(s), lane-partial l ----
            unsigned short* Pw = (unsigned short*)&U[w][0] + rt * 1152;
#pragma unroll
            for (int r = 0; r < 4; ++r) {
                const int row = q0 + rt * 16 + quad * 4 + r;
                float v0 = s[0][r], v1 = s[1][r], v2 = s[2][r], v3 = s[3][r];
                if (needmask) {
                    if (t0 + l16 > row) v0 = NEGINF;
                    if (t0 + 16 + l16 > row) v1 = NEGINF;
                    if (t0 + 32 + l16 > row) v2 = NEGINF;
                    if (t0 + 48 + l16 > row) v3 = NEGINF;
                }
                const float p0 = __builtin_amdgcn_exp2f(v0);
                const float p1 = __builtin_amdgcn_exp2f(v1);
                const float p2 = __builtin_amdgcn_exp2f(v2);
                const float p3 = __builtin_amdgcn_exp2f(v3);
                lp[rt][r] += (p0 + p1) + (p2 + p3);
                const int pr = (quad * 4 + r) * 72;
                Pw[pr + l16] = f2b(p0);
                Pw[pr + 16 + l16] = f2b(p1);
                Pw[pr + 32 + l16] = f2b(p2);
                Pw[pr + 48 + l16] = f2b(p3);
            }
            asm volatile("s_waitcnt lgkmcnt(0)" ::: "memory");  // per-wave P visibility
            bf16x8 aP[2];
            aP[0] = *(const bf16x8*)(Pw + l16 * 72 + quad * 8);
            aP[1] = *(const bf16x8*)(Pw + l16 * 72 + 32 + quad * 8);
#pragma unroll
            for (int ks = 0; ks < 2; ++ks)
#pragma unroll
                for (int nt = 0; nt < 4; ++nt)
                    o[rt][nt] = __builtin_amdgcn_mfma_f32_16x16x32_bf16(
                        aP[ks], bV[nt * 2 + ks], o[rt][nt], 0, 0, 0);
        }
    }

    // ---- reduce l (once), store o partials into this wave's union region ----
#pragma unroll
    for (int rt = 0; rt < 2; ++rt)
#pragma unroll
        for (int r = 0; r < 4; ++r) {
            const float lsum = dpp_sum16(lp[rt][r]);
            const int row = rt * 16 + quad * 4 + r;
            if (l16 == 0) lS[w][row] = lsum;
#pragma unroll
            for (int nt = 0; nt < 4; ++nt)
                U[w][row * 66 + nt * 16 + l16] = o[rt][nt][r];
        }
    __syncthreads();

    // ---- merge (plain sums — exact); wave w -> cols [w*16, +16) ----
    const int b = bh >> 4, h = bh & 15;
    const int col = w * 16 + l16;
#pragma unroll
    for (int rr = 0; rr < 8; ++rr) {
        const int row = quad * 8 + rr;
        const float L = (lS[0][row] + lS[1][row]) + (lS[2][row] + lS[3][row]);
        const float O = (U[0][row * 66 + col] + U[1][row * 66 + col]) +
                        (U[2][row * 66 + col] + U[3][row * 66 + col]);
        const int t = q0 + row;
        AO[((size_t)(b * TT + t)) * TC + h * 64 + col] = f2b(O / L);
    }
}

extern "C" void kernel_launch(void* const* d_in, const int* in_sizes, int n_in,
                              void* d_out, int out_size, void* d_ws, size_t ws_size,
                              hipStream_t stream) {
    const float* X = (const float*)d_in[0];      // [2,2048,1024] fp32
    const float* Wqkv = (const float*)d_in[1];   // [1024,3072] fp32
    const float* Wproj = (const float*)d_in[2];  // [1024,1024] fp32
    float* out = (float*)d_out;                  // [2,2048,1024] fp32

    unsigned short* ws = (unsigned short*)d_ws;
    unsigned short* Xb = ws;                           // [4096,1024] bf16
    unsigned short* Wq_t = Xb + 4096 * 1024;           // [3072,1024] bf16
    unsigned short* Wp_t = Wq_t + 3072 * 1024;         // [1024,1024] bf16
    unsigned short* Qb = Wp_t + 1024 * 1024;           // [B,H,T,64] (pre-scaled)
    unsigned short* Kb = Qb + TB * TH * TT * THS;      // [B,H,T,64]
    unsigned short* Vb = Kb + TB * TH * TT * THS;      // [B,H,T,64] (pre-transpose)
    unsigned short* Vt = Vb + TB * TH * TT * THS;      // [B,H,64,T]
    unsigned short* AO = Vt + TB * TH * TT * THS;      // [B,T,C] bf16

    cvt_bf16_k<<<dim3((4096 * 1024) / (8 * 256)), 256, 0, stream>>>(X, Xb);
    transpose_cvt_k<<<dim3(3072 / 32, 1024 / 32), dim3(32, 8), 0, stream>>>(Wqkv, Wq_t, 1024, 3072);
    transpose_cvt_k<<<dim3(1024 / 32, 1024 / 32), dim3(32, 8), 0, stream>>>(Wproj, Wp_t, 1024, 1024);
    gemm_qkv<<<dim3(3072 / 128, 4096 / 128), 256, 0, stream>>>(Xb, Wq_t, 1024, Kb, Qb, Vb);
    vt_k<<<dim3(THS / 32, TT / 32, TB * TH), dim3(32, 8), 0, stream>>>(Vb, Vt);
    attn_k<<<dim3(32, 64), 256, 0, stream>>>(Qb, Kb, Vt, AO);
    gemm_proj<<<dim3(1024 / 64, 4096 / 128), 256, 0, stream>>>(
        AO, Wp_t, 4096, 1024, 1024, out);
}

// Round 8
// 213.514 us; speedup vs baseline: 1.2978x; 1.0091x over previous
//
#include <hip/hip_runtime.h>

// Problem constants: B=2, T=2048, C=1024, H=16, HS=64. fp32 I/O, bf16 internal.
#define TB 2
#define TT 2048
#define TC 1024
#define TH 16
#define THS 64

typedef short bf16x8 __attribute__((ext_vector_type(8)));
typedef float f32x4 __attribute__((ext_vector_type(4)));

// Q pre-scale: (1/sqrt(C)) * log2(e), folded into Qb at QKV-GEMM epilogue
#define QSCALE 0.0450842200278f

// round-to-nearest-even fp32 -> bf16 bit pattern
__device__ inline unsigned short f2b(float f) {
    unsigned u = __builtin_bit_cast(unsigned, f);
    unsigned r = (u + 0x7fffu + ((u >> 16) & 1u)) >> 16;
    return (unsigned short)r;
}
__device__ inline float b2f(unsigned short h) {
    unsigned u = ((unsigned)h) << 16;
    return __builtin_bit_cast(float, u);
}

// async global->LDS 16B/lane. LDS dest contract: wave-uniform base + lane*16.
__device__ inline void gl_lds16(const unsigned short* g, unsigned short* l) {
    __builtin_amdgcn_global_load_lds(
        (const __attribute__((address_space(1))) unsigned int*)(g),
        (__attribute__((address_space(3))) unsigned int*)(l), 16, 0, 0);
}

// 16-lane all-reduce sum via DPP row_ror butterfly (once per row at kernel end)
__device__ inline float dpp_sum16(float x) {
    int t;
    t = __builtin_amdgcn_update_dpp(0, __builtin_bit_cast(int, x), 0x128, 0xf, 0xf, true);
    x += __builtin_bit_cast(float, t);
    t = __builtin_amdgcn_update_dpp(0, __builtin_bit_cast(int, x), 0x124, 0xf, 0xf, true);
    x += __builtin_bit_cast(float, t);
    t = __builtin_amdgcn_update_dpp(0, __builtin_bit_cast(int, x), 0x122, 0xf, 0xf, true);
    x += __builtin_bit_cast(float, t);
    t = __builtin_amdgcn_update_dpp(0, __builtin_bit_cast(int, x), 0x121, 0xf, 0xf, true);
    x += __builtin_bit_cast(float, t);
    return x;
}

// ---------------- convert fp32 -> bf16, 8 elements/thread ----------------
__global__ void cvt_bf16_k(const float* __restrict__ in, unsigned short* __restrict__ out) {
    const int i = blockIdx.x * blockDim.x + threadIdx.x;
    const float4* p = (const float4*)in + (size_t)i * 2;
    const float4 a = p[0], b = p[1];
    bf16x8 v;
    v[0] = (short)f2b(a.x); v[1] = (short)f2b(a.y);
    v[2] = (short)f2b(a.z); v[3] = (short)f2b(a.w);
    v[4] = (short)f2b(b.x); v[5] = (short)f2b(b.y);
    v[6] = (short)f2b(b.z); v[7] = (short)f2b(b.w);
    *(bf16x8*)(out + (size_t)i * 8) = v;
}

// ------------- transpose + convert: fp32 in[R][Cc] -> bf16 out[Cc][R] -------------
__global__ void transpose_cvt_k(const float* __restrict__ in,
                                unsigned short* __restrict__ out, int R, int Cc) {
    __shared__ float tile[32][33];
    const int tx = threadIdx.x, ty = threadIdx.y;
    const int r0 = blockIdx.y * 32, c0 = blockIdx.x * 32;
#pragma unroll
    for (int i = 0; i < 4; i++)
        tile[ty + i * 8][tx] = in[(size_t)(r0 + ty + i * 8) * Cc + c0 + tx];
    __syncthreads();
#pragma unroll
    for (int i = 0; i < 4; i++)
        out[(size_t)(c0 + ty + i * 8) * R + r0 + tx] = f2b(tile[tx][ty + i * 8]);
}

// ------ V transpose: Vb[bh][t][d] -> Vt[bh][d][t], bf16, coalesced both sides ----
__global__ void vt_k(const unsigned short* __restrict__ Vb,
                     unsigned short* __restrict__ Vt) {
    __shared__ unsigned short tile[32][33];
    const int tx = threadIdx.x, ty = threadIdx.y;
    const int d0 = blockIdx.x * 32, t0 = blockIdx.y * 32, bh = blockIdx.z;
    const unsigned short* src = Vb + (size_t)bh * TT * THS;
    unsigned short* dst = Vt + (size_t)bh * THS * TT;
#pragma unroll
    for (int i = 0; i < 4; i++)
        tile[ty + i * 8][tx] = src[(size_t)(t0 + ty + i * 8) * THS + d0 + tx];
    __syncthreads();
#pragma unroll
    for (int i = 0; i < 4; i++)
        dst[(size_t)(d0 + ty + i * 8) * TT + t0 + tx] = tile[tx][ty + i * 8];
}

// ------- QKV GEMM: C = Xb * Wq_t^T, scatter epilogue -> K/Q/V [B,H,T,64] ---------
__global__ __launch_bounds__(256) void gemm_qkv(
    const unsigned short* __restrict__ A, const unsigned short* __restrict__ Bt, int K,
    unsigned short* __restrict__ outK, unsigned short* __restrict__ outQ,
    unsigned short* __restrict__ outV) {
    __shared__ __align__(16) unsigned short As[128 * 32];
    __shared__ __align__(16) unsigned short Bs[128 * 32];

    const int tid = threadIdx.x;
    const int wave = tid >> 6, lane = tid & 63;
    const int quad = lane >> 4, l16 = lane & 15;
    const int wm = (wave >> 1) * 64, wn = (wave & 1) * 64;
    const int m0 = blockIdx.y * 128, n0 = blockIdx.x * 128;

    const f32x4 vzero = {0.f, 0.f, 0.f, 0.f};
    f32x4 acc[4][4];
#pragma unroll
    for (int i = 0; i < 4; i++)
#pragma unroll
        for (int j = 0; j < 4; j++) acc[i][j] = vzero;

    const int nk = K >> 5;
    for (int kt = 0; kt < nk; ++kt) {
        const int k0 = kt * 32;
        __syncthreads();
#pragma unroll
        for (int it = 0; it < 2; ++it) {
            const int chunk = tid + it * 256;
            const int r = chunk >> 2, col = (chunk & 3) * 8;
            gl_lds16(A + (size_t)(m0 + r) * K + k0 + col, &As[chunk * 8]);
            gl_lds16(Bt + (size_t)(n0 + r) * K + k0 + col, &Bs[chunk * 8]);
        }
        __syncthreads();
        bf16x8 af[4], bfr[4];
#pragma unroll
        for (int f = 0; f < 4; ++f) {
            af[f] = *(const bf16x8*)(&As[(wm + f * 16 + l16) * 32 + quad * 8]);
            bfr[f] = *(const bf16x8*)(&Bs[(wn + f * 16 + l16) * 32 + quad * 8]);
        }
#pragma unroll
        for (int fm = 0; fm < 4; ++fm)
#pragma unroll
            for (int fn = 0; fn < 4; ++fn)
                acc[fm][fn] = __builtin_amdgcn_mfma_f32_16x16x32_bf16(
                    af[fm], bfr[fn], acc[fm][fn], 0, 0, 0);
    }

    // epilogue: C/D layout col=lane&15, row=quad*4+reg
#pragma unroll
    for (int fm = 0; fm < 4; ++fm) {
#pragma unroll
        for (int fn = 0; fn < 4; ++fn) {
#pragma unroll
            for (int r = 0; r < 4; ++r) {
                const int row = m0 + wm + fm * 16 + quad * 4 + r;
                const int col = n0 + wn + fn * 16 + l16;
                const float val = acc[fm][fn][r];
                const int b = row >> 11, t = row & (TT - 1);
                const int chunkc = col >> 10, cc = col & (TC - 1);
                const int hh = cc >> 6, d = cc & 63;
                const size_t idx = (size_t)((b * TH + hh) * TT + t) * THS + d;
                if (chunkc == 0)
                    outK[idx] = f2b(val);  // module split order: K first!
                else if (chunkc == 1)
                    outQ[idx] = f2b(val * QSCALE);  // pre-scaled Q
                else
                    outV[idx] = f2b(val);  // coalesced; vt_k transposes after
            }
        }
    }
}

// ------- proj GEMM: out[M,N] = A[M,K] * Bt[N,K]^T, 128x64 tile, fp32 out ---------
__global__ __launch_bounds__(256) void gemm_proj(
    const unsigned short* __restrict__ A, const unsigned short* __restrict__ Bt,
    int M, int N, int K, float* __restrict__ outF) {
    __shared__ __align__(16) unsigned short As[128 * 32];
    __shared__ __align__(16) unsigned short Bs[64 * 32];

    const int tid = threadIdx.x;
    const int wave = tid >> 6, lane = tid & 63;
    const int quad = lane >> 4, l16 = lane & 15;
    const int wm = wave * 32;
    const int m0 = blockIdx.y * 128, n0 = blockIdx.x * 64;

    const f32x4 vzero = {0.f, 0.f, 0.f, 0.f};
    f32x4 acc[2][4];
#pragma unroll
    for (int i = 0; i < 2; i++)
#pragma unroll
        for (int j = 0; j < 4; j++) acc[i][j] = vzero;

    const int nk = K >> 5;
    for (int kt = 0; kt < nk; ++kt) {
        const int k0 = kt * 32;
        __syncthreads();
#pragma unroll
        for (int it = 0; it < 2; ++it) {
            const int chunk = tid + it * 256;
            const int r = chunk >> 2, col = (chunk & 3) * 8;
            gl_lds16(A + (size_t)(m0 + r) * K + k0 + col, &As[chunk * 8]);
        }
        {
            const int r = tid >> 2, col = (tid & 3) * 8;
            gl_lds16(Bt + (size_t)(n0 + r) * K + k0 + col, &Bs[tid * 8]);
        }
        __syncthreads();
        bf16x8 af[2], bfr[4];
#pragma unroll
        for (int f = 0; f < 2; ++f)
            af[f] = *(const bf16x8*)(&As[(wm + f * 16 + l16) * 32 + quad * 8]);
#pragma unroll
        for (int f = 0; f < 4; ++f)
            bfr[f] = *(const bf16x8*)(&Bs[(f * 16 + l16) * 32 + quad * 8]);
#pragma unroll
        for (int fm = 0; fm < 2; ++fm)
#pragma unroll
            for (int fn = 0; fn < 4; ++fn)
                acc[fm][fn] = __builtin_amdgcn_mfma_f32_16x16x32_bf16(
                    af[fm], bfr[fn], acc[fm][fn], 0, 0, 0);
    }

#pragma unroll
    for (int fm = 0; fm < 2; ++fm)
#pragma unroll
        for (int fn = 0; fn < 4; ++fn)
#pragma unroll
            for (int r = 0; r < 4; ++r) {
                const int row = m0 + wm + fm * 16 + quad * 4 + r;
                const int col = n0 + fn * 16 + l16;
                outF[(size_t)row * N + col] = acc[fm][fn][r];
            }
}

// ---- flash attention, no-max softmax + in-block split-K, 32 q-rows/block ----
// LDS budget is the occupancy binder (VGPR=84 allows 6 waves/SIMD): per-wave union
// region serves as P staging (2x16x72 u16 = 4608 B) during the loop and as the
// bf16 o-partial buffer (32 rows x stride 66 u16 = 4224 B) at merge. Block LDS
// ~18.9 KB -> 6 blocks/CU co-resident. NO aggressive launch_bounds (R6: spills).
__global__ __launch_bounds__(256, 3) void attn_k(
    const unsigned short* __restrict__ Qb, const unsigned short* __restrict__ Kb,
    const unsigned short* __restrict__ Vt, unsigned short* __restrict__ AO) {
    __shared__ __align__(16) unsigned short U[4][2304];  // per-wave union: P / oS(bf16)
    __shared__ float lS[4][32];                          // per-wave l per row

    const int tid = threadIdx.x;
    const int w = tid >> 6, lane = tid & 63;
    const int quad = lane >> 4, l16 = lane & 15;
    const int bh = blockIdx.x;        // 0..31 (fastest: spreads long blocks)
    const int qtt = 63 - blockIdx.y;  // reversed: longest blocks dispatch first
    const int q0 = qtt * 32;
    const unsigned short* Qh = Qb + (size_t)bh * TT * THS;
    const unsigned short* Kh = Kb + (size_t)bh * TT * THS;
    const unsigned short* Vh = Vt + (size_t)bh * THS * TT;

    bf16x8 aQ[2][2];
#pragma unroll
    for (int rt = 0; rt < 2; ++rt)
#pragma unroll
        for (int ks = 0; ks < 2; ++ks)
            aQ[rt][ks] = *(const bf16x8*)(
                Qh + (size_t)(q0 + rt * 16 + l16) * THS + ks * 32 + quad * 8);

    const float NEGINF = -__builtin_inff();
    const f32x4 vzero = {0.f, 0.f, 0.f, 0.f};
    f32x4 o[2][4];
    float lp[2][4];  // per-lane l partials
#pragma unroll
    for (int rt = 0; rt < 2; ++rt)
#pragma unroll
        for (int i = 0; i < 4; i++) { o[rt][i] = vzero; lp[rt][i] = 0.f; }

    const int nkt = (qtt >> 1) + 1;  // 64-key tiles covering [0, q0+32)
    for (int kt = w; kt < nkt; kt += 4) {
        const int t0 = kt * 64;
        // ---- K and V fragment loads (compiler schedules; V used only in PV) ----
        bf16x8 bK[8], bV[8];
#pragma unroll
        for (int nt = 0; nt < 4; ++nt)
#pragma unroll
            for (int ks = 0; ks < 2; ++ks) {
                bK[nt * 2 + ks] = *(const bf16x8*)(
                    Kh + (size_t)(t0 + nt * 16 + l16) * THS + ks * 32 + quad * 8);
                bV[nt * 2 + ks] = *(const bf16x8*)(
                    Vh + (size_t)(nt * 16 + l16) * TT + t0 + ks * 32 + quad * 8);
            }
        const bool needmask = (kt == nkt - 1);  // only the diagonal tile masks
        // ---- QK^T + softmax + P write, both row-tiles; ONE LDS drain ----
#pragma unroll
        for (int rt = 0; rt < 2; ++rt) {
            f32x4 s[4];
#pragma unroll
            for (int nt = 0; nt < 4; ++nt) s[nt] = vzero;
#pragma unroll
            for (int ks = 0; ks < 2; ++ks)
#pragma unroll
                for (int nt = 0; nt < 4; ++nt)
                    s[nt] = __builtin_amdgcn_mfma_f32_16x16x32_bf16(
                        aQ[rt][ks], bK[nt * 2 + ks], s[nt], 0, 0, 0);
            unsigned short* Pw = &U[w][0] + rt * 1152;  // 16 rows x stride 72
#pragma unroll
            for (int r = 0; r < 4; ++r) {
                const int row = q0 + rt * 16 + quad * 4 + r;
                float v0 = s[0][r], v1 = s[1][r], v2 = s[2][r], v3 = s[3][r];
                if (needmask) {
                    if (t0 + l16 > row) v0 = NEGINF;
                    if (t0 + 16 + l16 > row) v1 = NEGINF;
                    if (t0 + 32 + l16 > row) v2 = NEGINF;
                    if (t0 + 48 + l16 > row) v3 = NEGINF;
                }
                const float p0 = __builtin_amdgcn_exp2f(v0);
                const float p1 = __builtin_amdgcn_exp2f(v1);
                const float p2 = __builtin_amdgcn_exp2f(v2);
                const float p3 = __builtin_amdgcn_exp2f(v3);
                lp[rt][r] += (p0 + p1) + (p2 + p3);
                const int pr = (quad * 4 + r) * 72;
                Pw[pr + l16] = f2b(p0);
                Pw[pr + 16 + l16] = f2b(p1);
                Pw[pr + 32 + l16] = f2b(p2);
                Pw[pr + 48 + l16] = f2b(p3);
            }
        }
        asm volatile("s_waitcnt lgkmcnt(0)" ::: "memory");  // per-wave P visibility
        bf16x8 aP[2][2];
#pragma unroll
        for (int rt = 0; rt < 2; ++rt) {
            const unsigned short* Pw = &U[w][0] + rt * 1152;
            aP[rt][0] = *(const bf16x8*)(Pw + l16 * 72 + quad * 8);
            aP[rt][1] = *(const bf16x8*)(Pw + l16 * 72 + 32 + quad * 8);
        }
#pragma unroll
        for (int rt = 0; rt < 2; ++rt)
#pragma unroll
            for (int ks = 0; ks < 2; ++ks)
#pragma unroll
                for (int nt = 0; nt < 4; ++nt)
                    o[rt][nt] = __builtin_amdgcn_mfma_f32_16x16x32_bf16(
                        aP[rt][ks], bV[nt * 2 + ks], o[rt][nt], 0, 0, 0);
    }

    // ---- reduce l (once), store bf16 o partials into this wave's union region ----
    // Safe aliasing with P: this wave's last aP read precedes its own oS writes;
    // other waves read only after __syncthreads.
#pragma unroll
    for (int rt = 0; rt < 2; ++rt)
#pragma unroll
        for (int r = 0; r < 4; ++r) {
            const float lsum = dpp_sum16(lp[rt][r]);
            const int row = rt * 16 + quad * 4 + r;
            if (l16 == 0) lS[w][row] = lsum;
#pragma unroll
            for (int nt = 0; nt < 4; ++nt)
                U[w][row * 66 + nt * 16 + l16] = f2b(o[rt][nt][r]);
        }
    __syncthreads();

    // ---- merge (plain sums — exact); wave w -> cols [w*16, +16) ----
    const int b = bh >> 4, h = bh & 15;
    const int col = w * 16 + l16;
#pragma unroll
    for (int rr = 0; rr < 8; ++rr) {
        const int row = quad * 8 + rr;
        const float L = (lS[0][row] + lS[1][row]) + (lS[2][row] + lS[3][row]);
        const float O = (b2f(U[0][row * 66 + col]) + b2f(U[1][row * 66 + col])) +
                        (b2f(U[2][row * 66 + col]) + b2f(U[3][row * 66 + col]));
        const int t = q0 + row;
        AO[((size_t)(b * TT + t)) * TC + h * 64 + col] = f2b(O * __builtin_amdgcn_rcpf(L));
    }
}

extern "C" void kernel_launch(void* const* d_in, const int* in_sizes, int n_in,
                              void* d_out, int out_size, void* d_ws, size_t ws_size,
                              hipStream_t stream) {
    const float* X = (const float*)d_in[0];      // [2,2048,1024] fp32
    const float* Wqkv = (const float*)d_in[1];   // [1024,3072] fp32
    const float* Wproj = (const float*)d_in[2];  // [1024,1024] fp32
    float* out = (float*)d_out;                  // [2,2048,1024] fp32

    unsigned short* ws = (unsigned short*)d_ws;
    unsigned short* Xb = ws;                           // [4096,1024] bf16
    unsigned short* Wq_t = Xb + 4096 * 1024;           // [3072,1024] bf16
    unsigned short* Wp_t = Wq_t + 3072 * 1024;         // [1024,1024] bf16
    unsigned short* Qb = Wp_t + 1024 * 1024;           // [B,H,T,64] (pre-scaled)
    unsigned short* Kb = Qb + TB * TH * TT * THS;      // [B,H,T,64]
    unsigned short* Vb = Kb + TB * TH * TT * THS;      // [B,H,T,64] (pre-transpose)
    unsigned short* Vt = Vb + TB * TH * TT * THS;      // [B,H,64,T]
    unsigned short* AO = Vt + TB * TH * TT * THS;      // [B,T,C] bf16

    cvt_bf16_k<<<dim3((4096 * 1024) / (8 * 256)), 256, 0, stream>>>(X, Xb);
    transpose_cvt_k<<<dim3(3072 / 32, 1024 / 32), dim3(32, 8), 0, stream>>>(Wqkv, Wq_t, 1024, 3072);
    transpose_cvt_k<<<dim3(1024 / 32, 1024 / 32), dim3(32, 8), 0, stream>>>(Wproj, Wp_t, 1024, 1024);
    gemm_qkv<<<dim3(3072 / 128, 4096 / 128), 256, 0, stream>>>(Xb, Wq_t, 1024, Kb, Qb, Vb);
    vt_k<<<dim3(THS / 32, TT / 32, TB * TH), dim3(32, 8), 0, stream>>>(Vb, Vt);
    attn_k<<<dim3(32, 64), 256, 0, stream>>>(Qb, Kb, Vt, AO);
    gemm_proj<<<dim3(1024 / 64, 4096 / 128), 256, 0, stream>>>(
        AO, Wp_t, 4096, 1024, 1024, out);
}